// Round 10
// baseline (445.165 us; speedup 1.0000x reference)
//
#include <hip/hip_runtime.h>

// ---------------- constants ----------------
#define D_MODEL 768
#define D_INNER 1536
#define NXZ     3072   // 2*D_INNER
#define BATCH   2
#define SEQ     8192
#define MTOT    (BATCH*SEQ)   // 16384
#define WARM    64            // 0.9^64 ~ 1.2e-3; output-level error ~1e-6 << 3.5e-4 threshold

typedef _Float16 v8h __attribute__((ext_vector_type(8)));
typedef _Float16 v4h __attribute__((ext_vector_type(4)));
typedef float    v4f __attribute__((ext_vector_type(4)));
typedef _Float16 f16;

// fast reciprocal (v_rcp_f32, ~1 ulp) -- avoids the precise-div sequence
__device__ __forceinline__ float frcp(float x) {
  float r;
  asm volatile("v_rcp_f32 %0, %1" : "=v"(r) : "v"(x));
  return r;
}
__device__ __forceinline__ float fsilu(float u) {
  return u * frcp(1.f + __expf(-u));
}

// ---------------- fused prep: cvt + two transposes in ONE launch ----------------
#define NCVT (MTOT * D_MODEL / 4 / 256)          // 12288
#define NT1  ((NXZ / 32) * (D_MODEL / 32))       // 96*24 = 2304
#define NT2  ((D_MODEL / 32) * (D_INNER / 32))   // 24*48 = 1152

__device__ __forceinline__ void transpose_tile(const float* __restrict__ in,
                                               f16* __restrict__ out,
                                               int R, int C, int bx, int by, int tid) {
  __shared__ float tile[32][33];
  const int c0 = bx * 32, r0 = by * 32;
  const int tx = tid & 31, ty = tid >> 5;   // 32 x 8
#pragma unroll
  for (int i = 0; i < 32; i += 8)
    tile[ty + i][tx] = in[(long)(r0 + ty + i) * C + (c0 + tx)];
  __syncthreads();
#pragma unroll
  for (int i = 0; i < 32; i += 8)
    out[(long)(c0 + ty + i) * R + (r0 + tx)] = (f16)tile[tx][ty + i];
}

__global__ void k_prep(const float* __restrict__ x, f16* __restrict__ xb,
                       const float* __restrict__ in_w, f16* __restrict__ wInT,
                       const float* __restrict__ out_w, f16* __restrict__ wOutT) {
  const int bid = blockIdx.x;
  const int tid = threadIdx.x;
  if (bid < NCVT) {
    const int i = bid * 256 + tid;
    float4 v = reinterpret_cast<const float4*>(x)[i];
    v4h o;
    o[0] = (f16)v.x; o[1] = (f16)v.y; o[2] = (f16)v.z; o[3] = (f16)v.w;
    reinterpret_cast<v4h*>(xb)[i] = o;
  } else if (bid < NCVT + NT1) {
    const int b2 = bid - NCVT;
    transpose_tile(in_w, wInT, D_MODEL, NXZ, b2 % (NXZ / 32), b2 / (NXZ / 32), tid);
  } else {
    const int b2 = bid - NCVT - NT1;
    transpose_tile(out_w, wOutT, D_INNER, D_MODEL, b2 % (D_MODEL / 32), b2 / (D_MODEL / 32), tid);
  }
}

// async global->LDS, 16B per lane, dest = wave-uniform base + lane*16
__device__ __forceinline__ void gload_lds16(const void* g, void* l) {
  __builtin_amdgcn_global_load_lds((const __attribute__((address_space(1))) void*)g,
                                   (__attribute__((address_space(3))) void*)l, 16, 0, 0);
}

// ---------------- MFMA GEMM (R2 core): single buffer, TRANSPOSED f16 out ----------------
// BM=128 x BN=128 x BK=64, 4 waves, acc[4][4]. Swizzle: phys_chunk =
// logical_chunk ^ (row&7); stage side pre-swizzles the GLOBAL source chunk
// (lane&7)^(lane>>3); read side phys col ((quad^(m16&7))<<3) / ^32.
// 0 bank conflicts measured (R2).
// R10: epilogue writes C TRANSPOSED as f16 CT[n][m] (row stride M): each
// lane owns 4 CONSECUTIVE m (quad*4+r) at fixed n -> one 8B v4h store per
// (i,j); 16 store insts (vs 64 x 2B before). Sole consumer (conv scan) then
// reads time-contiguous rows.
__launch_bounds__(256, 2)
__global__ void k_gemm_bt_T(const f16* __restrict__ A, const f16* __restrict__ Bt,
                            const float* __restrict__ bias, f16* __restrict__ CT,
                            int M, int N, int K) {
  __shared__ f16 As[128][64];   // 16 KB
  __shared__ f16 Bs[128][64];   // 16 KB
  const int tid  = threadIdx.x;
  const int lane = tid & 63;
  const int wave = tid >> 6;
  const int wm   = (wave >> 1) * 64;
  const int wn   = (wave & 1) * 64;
  const int m16  = lane & 15;
  const int quad = lane >> 4;
  const long m0 = (long)blockIdx.y * 128;
  const long n0 = (long)blockIdx.x * 128;

  v4f acc[4][4];
#pragma unroll
  for (int i = 0; i < 4; i++)
#pragma unroll
    for (int j = 0; j < 4; j++)
#pragma unroll
      for (int r = 0; r < 4; r++) acc[i][j][r] = 0.f;

  const int  srow = wave * 8 + (lane >> 3);
  const int  gcol = ((lane & 7) ^ (lane >> 3)) << 3;
  const f16* Ag = A  + (m0 + srow) * (long)K + gcol;
  const f16* Bg = Bt + (n0 + srow) * (long)K + gcol;

  const int c0q = ((quad ^ (m16 & 7)) << 3);   // phys col (f16), k-half 0
  const int c1q = c0q ^ 32;                    // k-half 1

  for (int k0 = 0; k0 < K; k0 += 64) {
#pragma unroll
    for (int g = 0; g < 4; ++g) {
      gload_lds16(Ag + (long)(g * 32) * K, &As[wave * 8 + g * 32][0]);
      gload_lds16(Bg + (long)(g * 32) * K, &Bs[wave * 8 + g * 32][0]);
    }
    Ag += 64; Bg += 64;
    __syncthreads();                // drains vmcnt -> staged tile visible
    v8h af[4], bfr[4];
#pragma unroll
    for (int i = 0; i < 4; i++) af[i]  = *(const v8h*)&As[wm + i * 16 + m16][c0q];
#pragma unroll
    for (int j = 0; j < 4; j++) bfr[j] = *(const v8h*)&Bs[wn + j * 16 + m16][c0q];
#pragma unroll
    for (int i = 0; i < 4; i++)
#pragma unroll
      for (int j = 0; j < 4; j++)
        acc[i][j] = __builtin_amdgcn_mfma_f32_16x16x32_f16(af[i], bfr[j], acc[i][j], 0, 0, 0);
#pragma unroll
    for (int i = 0; i < 4; i++) af[i]  = *(const v8h*)&As[wm + i * 16 + m16][c1q];
#pragma unroll
    for (int j = 0; j < 4; j++) bfr[j] = *(const v8h*)&Bs[wn + j * 16 + m16][c1q];
#pragma unroll
    for (int i = 0; i < 4; i++)
#pragma unroll
      for (int j = 0; j < 4; j++)
        acc[i][j] = __builtin_amdgcn_mfma_f32_16x16x32_f16(af[i], bfr[j], acc[i][j], 0, 0, 0);
    __syncthreads();                // protect LDS before next stage
  }

  // transposed epilogue: CT[n][m], lane writes 4 consecutive m as one v4h
#pragma unroll
  for (int i = 0; i < 4; i++) {
    const long mB = m0 + wm + i * 16 + quad * 4;
#pragma unroll
    for (int j = 0; j < 4; j++) {
      const long n = n0 + wn + j * 16 + m16;
      const float bv = bias[n];
      v4h o;
#pragma unroll
      for (int r = 0; r < 4; r++) o[r] = (f16)(acc[i][j][r] + bv);
      *(v4h*)&CT[n * (long)M + mB] = o;
    }
  }
}

// ---------------- MFMA GEMM BM=256 (R3-proven, for the small-N GEMM2) ----------------
template <bool F16OUT>
__launch_bounds__(256, 2)
__global__ void k_gemm_big(const f16* __restrict__ A, const f16* __restrict__ Bt,
                           const float* __restrict__ bias, void* __restrict__ Cv,
                           int M, int N, int K) {
  __shared__ f16 As[256][64];   // 32 KB
  __shared__ f16 Bs[128][64];   // 16 KB
  const int tid  = threadIdx.x;
  const int lane = tid & 63;
  const int wave = tid >> 6;
  const int wm   = (wave >> 1) * 128;   // wave row base (2 waves in M)
  const int wn   = (wave & 1) * 64;     // wave col base (2 waves in N)
  const int m16  = lane & 15;
  const int quad = lane >> 4;
  const long m0 = (long)blockIdx.y * 256;
  const long n0 = (long)blockIdx.x * 128;

  v4f acc[8][4];
#pragma unroll
  for (int i = 0; i < 8; i++)
#pragma unroll
    for (int j = 0; j < 4; j++)
#pragma unroll
      for (int r = 0; r < 4; r++) acc[i][j][r] = 0.f;

  const int  srow = wave * 8 + (lane >> 3);
  const int  gcol = ((lane & 7) ^ (lane >> 3)) << 3;
  const f16* Ag = A  + (m0 + srow) * (long)K + gcol;
  const f16* Bg = Bt + (n0 + srow) * (long)K + gcol;
  f16* AsW = &As[wave * 8][0];   // wave-uniform dest bases
  f16* BsW = &Bs[wave * 8][0];

  const int c0q = ((quad ^ (m16 & 7)) << 3);   // phys col (f16), k-half 0
  const int c1q = c0q ^ 32;                    // k-half 1

  for (int k0 = 0; k0 < K; k0 += 64) {
#pragma unroll
    for (int g = 0; g < 8; ++g)
      gload_lds16(Ag + (long)(g * 32) * K, AsW + g * 32 * 64);
#pragma unroll
    for (int g = 0; g < 4; ++g)
      gload_lds16(Bg + (long)(g * 32) * K, BsW + g * 32 * 64);
    Ag += 64; Bg += 64;
    __syncthreads();
    v8h bfr[4], af;
#pragma unroll
    for (int j = 0; j < 4; j++) bfr[j] = *(const v8h*)&Bs[wn + j * 16 + m16][c0q];
#pragma unroll
    for (int i = 0; i < 8; i++) {
      af = *(const v8h*)&As[wm + i * 16 + m16][c0q];
#pragma unroll
      for (int j = 0; j < 4; j++)
        acc[i][j] = __builtin_amdgcn_mfma_f32_16x16x32_f16(af, bfr[j], acc[i][j], 0, 0, 0);
    }
#pragma unroll
    for (int j = 0; j < 4; j++) bfr[j] = *(const v8h*)&Bs[wn + j * 16 + m16][c1q];
#pragma unroll
    for (int i = 0; i < 8; i++) {
      af = *(const v8h*)&As[wm + i * 16 + m16][c1q];
#pragma unroll
      for (int j = 0; j < 4; j++)
        acc[i][j] = __builtin_amdgcn_mfma_f32_16x16x32_f16(af, bfr[j], acc[i][j], 0, 0, 0);
    }
    __syncthreads();
  }

#pragma unroll
  for (int i = 0; i < 8; i++) {
#pragma unroll
    for (int j = 0; j < 4; j++) {
      const long n = n0 + wn + j * 16 + m16;
      const float bv = bias[n];
#pragma unroll
      for (int r = 0; r < 4; r++) {
        const long m = m0 + wm + i * 16 + quad * 4 + r;
        float v = acc[i][j][r] + bv;
        if (F16OUT) ((f16*)Cv)[m * N + n] = (f16)v;
        else        ((float*)Cv)[m * N + n] = v;
      }
    }
  }
}

// ---------------- conv4 + SiLU + EMA scan + gate (R10: transposed input) ----------------
// xzT is [channel 3072][token 16384]: each thread's t-walk is CONTIGUOUS ->
// one v8h (16B) load per 8 timesteps instead of 8 strided scalar loads.
// Removes ~8 VALU addr-ops/iter and shrinks outstanding loads 16 -> 2/batch;
// the single next-batch load prefetches under the ~350-cyc serial EMA chain.
// y stays [m][c] (lane-coalesced stores; G2 unchanged).
__launch_bounds__(256, 4)
__global__ void k_conv_scan(const f16* __restrict__ xzT, const float* __restrict__ conv_w,
                            const float* __restrict__ conv_b, const float* __restrict__ Dp_,
                            f16* __restrict__ y) {
  const int tid = threadIdx.x;
  const int c   = blockIdx.y * 256 + tid;
  const int b   = blockIdx.z;
  const int t0  = blockIdx.x * 64;     // output window [t0, t0+64)
  const float w0 = conv_w[c * 4 + 0], w1 = conv_w[c * 4 + 1];
  const float w2 = conv_w[c * 4 + 2], w3 = conv_w[c * 4 + 3];
  const float cb = conv_b[c], Dp = Dp_[c];
  const long mb = (long)b * SEQ;

  const f16* xr = xzT + (long)c * MTOT + mb;                 // x[t] = xr[t]
  const f16* zr = xzT + (long)(D_INNER + c) * MTOT + mb;     // z[t] = zr[t]
  f16*       yc = y + (mb + t0) * (long)D_INNER + c;         // y[t0+u][c]

  float xm3 = 0.f, xm2 = 0.f, xm1 = 0.f, h = 0.f;
  const int ts = t0 - WARM;
  if (t0 > 0) {
    xm3 = (float)xr[ts - 3];
    xm2 = (float)xr[ts - 2];
    xm1 = (float)xr[ts - 1];
    // warm-up: EMA only, no output; 8 x v8h batches
#pragma unroll 1
    for (int tb = 0; tb < 8; ++tb) {
      const v8h xv = *(const v8h*)&xr[ts + tb * 8];
#pragma unroll
      for (int e = 0; e < 8; ++e) {
        float xt = (float)xv[e];
        float u  = w0 * xm3 + w1 * xm2 + w2 * xm1 + w3 * xt + cb;
        h = 0.9f * h + 0.1f * fsilu(u);
        xm3 = xm2; xm2 = xm1; xm1 = xt;
      }
    }
  }

  // main: 64 outputs; 8 x (v8h x, v8h z) batches
#pragma unroll 1
  for (int tb = 0; tb < 8; ++tb) {
    const v8h xv = *(const v8h*)&xr[t0 + tb * 8];
    const v8h zv = *(const v8h*)&zr[t0 + tb * 8];
#pragma unroll
    for (int e = 0; e < 8; ++e) {
      float xt = (float)xv[e];
      float u  = w0 * xm3 + w1 * xm2 + w2 * xm1 + w3 * xt + cb;
      float v  = fsilu(u);
      h = 0.9f * h + 0.1f * v;
      float g  = fsilu((float)zv[e]);
      yc[(long)(tb * 8 + e) * D_INNER] = (f16)((v * Dp + h) * g);
      xm3 = xm2; xm2 = xm1; xm1 = xt;
    }
  }
}

// ---------------- launch ----------------
extern "C" void kernel_launch(void* const* d_in, const int* in_sizes, int n_in,
                              void* d_out, int out_size, void* d_ws, size_t ws_size,
                              hipStream_t stream) {
  const float* x       = (const float*)d_in[0];
  const float* in_w    = (const float*)d_in[1];
  const float* in_b    = (const float*)d_in[2];
  const float* conv_w  = (const float*)d_in[3];
  const float* conv_b  = (const float*)d_in[4];
  // d_in[5..8] (xp_w, xp_b, dt_w, dt_b) are dead code in the reference
  const float* D_param = (const float*)d_in[9];
  const float* out_w   = (const float*)d_in[10];
  const float* out_b   = (const float*)d_in[11];
  float* out = (float*)d_out;

  char* p = (char*)d_ws;
  f16* xb    = (f16*)p; p += (size_t)MTOT * D_MODEL * 2;   // 25.2 MB
  f16* wInT  = (f16*)p; p += (size_t)NXZ * D_MODEL * 2;    //  4.7 MB
  f16* wOutT = (f16*)p; p += (size_t)D_MODEL * D_INNER * 2;//  2.4 MB
  f16* xzT   = (f16*)p; p += (size_t)NXZ * MTOT * 2;       // 100.7 MB ([n][m] transposed)
  f16* yb    = (f16*)p; p += (size_t)MTOT * D_INNER * 2;   // 50.3 MB ([m][c])

  // fused prep: cvt + both weight transposes
  k_prep<<<NCVT + NT1 + NT2, 256, 0, stream>>>(x, xb, in_w, wInT, out_w, wOutT);

  // xzT = (x @ in_w + in_b)^T  (f16, [n][m]); transposed epilogue
  k_gemm_bt_T<<<dim3(NXZ / 128, MTOT / 128), 256, 0, stream>>>(xb, wInT, in_b, xzT, MTOT, NXZ, D_MODEL);

  // conv + silu + EMA scan + gate -> y (f16, [m][c]); time-contiguous reads
  k_conv_scan<<<dim3(SEQ / 64, D_INNER / 256, BATCH), 256, 0, stream>>>(xzT, conv_w, conv_b, D_param, yb);

  // out = y @ out_w + out_b  (f32, [m][n]); BM=256 variant (R3-proven, 384 blocks)
  k_gemm_big<false><<<dim3(D_MODEL / 128, MTOT / 256), 256, 0, stream>>>(yb, wOutT, out_b, out, MTOT, D_MODEL, D_INNER);
}

// Round 12
// 300.344 us; speedup vs baseline: 1.4822x; 1.4822x over previous
//
#include <hip/hip_runtime.h>

// ---------------- constants ----------------
#define D_MODEL 768
#define D_INNER 1536
#define NXZ     3072   // 2*D_INNER
#define BATCH   2
#define SEQ     8192
#define MTOT    (BATCH*SEQ)   // 16384
#define WARM    64            // 0.9^64 ~ 1.2e-3; output-level error ~1e-6 << 3.5e-4 threshold

typedef _Float16 v8h __attribute__((ext_vector_type(8)));
typedef _Float16 v4h __attribute__((ext_vector_type(4)));
typedef float    v4f __attribute__((ext_vector_type(4)));
typedef _Float16 f16;

// fast reciprocal (v_rcp_f32, ~1 ulp)
__device__ __forceinline__ float frcp(float x) {
  float r;
  asm volatile("v_rcp_f32 %0, %1" : "=v"(r) : "v"(x));
  return r;
}
__device__ __forceinline__ float fsilu(float u) {
  return u * frcp(1.f + __expf(-u));
}

// ---------------- fused prep: cvt + two transposes in ONE launch ----------------
#define NCVT (MTOT * D_MODEL / 4 / 256)          // 12288
#define NT1  ((NXZ / 32) * (D_MODEL / 32))       // 96*24 = 2304
#define NT2  ((D_MODEL / 32) * (D_INNER / 32))   // 24*48 = 1152

__device__ __forceinline__ void transpose_tile(const float* __restrict__ in,
                                               f16* __restrict__ out,
                                               int R, int C, int bx, int by, int tid) {
  __shared__ float tile[32][33];
  const int c0 = bx * 32, r0 = by * 32;
  const int tx = tid & 31, ty = tid >> 5;   // 32 x 8
#pragma unroll
  for (int i = 0; i < 32; i += 8)
    tile[ty + i][tx] = in[(long)(r0 + ty + i) * C + (c0 + tx)];
  __syncthreads();
#pragma unroll
  for (int i = 0; i < 32; i += 8)
    out[(long)(c0 + ty + i) * R + (r0 + tx)] = (f16)tile[tx][ty + i];
}

__global__ void k_prep(const float* __restrict__ x, f16* __restrict__ xb,
                       const float* __restrict__ in_w, f16* __restrict__ wInT,
                       const float* __restrict__ out_w, f16* __restrict__ wOutT) {
  const int bid = blockIdx.x;
  const int tid = threadIdx.x;
  if (bid < NCVT) {
    const int i = bid * 256 + tid;
    float4 v = reinterpret_cast<const float4*>(x)[i];
    v4h o;
    o[0] = (f16)v.x; o[1] = (f16)v.y; o[2] = (f16)v.z; o[3] = (f16)v.w;
    reinterpret_cast<v4h*>(xb)[i] = o;
  } else if (bid < NCVT + NT1) {
    const int b2 = bid - NCVT;
    transpose_tile(in_w, wInT, D_MODEL, NXZ, b2 % (NXZ / 32), b2 / (NXZ / 32), tid);
  } else {
    const int b2 = bid - NCVT - NT1;
    transpose_tile(out_w, wOutT, D_INNER, D_MODEL, b2 % (D_MODEL / 32), b2 / (D_MODEL / 32), tid);
  }
}

// async global->LDS, 16B per lane, dest = wave-uniform base + lane*16
__device__ __forceinline__ void gload_lds16(const void* g, void* l) {
  __builtin_amdgcn_global_load_lds((const __attribute__((address_space(1))) void*)g,
                                   (__attribute__((address_space(3))) void*)l, 16, 0, 0);
}

// ---------------- MFMA GEMM (R2-exact, proven 864 TF): single buffer ----------------
// BM=128 x BN=128 x BK=64, 4 waves, acc[4][4]. Swizzle: phys_chunk =
// logical_chunk ^ (row&7); stage side pre-swizzles the GLOBAL source chunk
// (lane&7)^(lane>>3); read side phys col ((quad^(m16&7))<<3) / ^32.
// 0 bank conflicts measured (R2).
template <bool F16OUT>
__launch_bounds__(256, 2)
__global__ void k_gemm_bt(const f16* __restrict__ A, const f16* __restrict__ Bt,
                          const float* __restrict__ bias, void* __restrict__ Cv,
                          int M, int N, int K) {
  __shared__ f16 As[128][64];   // 16 KB
  __shared__ f16 Bs[128][64];   // 16 KB
  const int tid  = threadIdx.x;
  const int lane = tid & 63;
  const int wave = tid >> 6;
  const int wm   = (wave >> 1) * 64;
  const int wn   = (wave & 1) * 64;
  const int m16  = lane & 15;
  const int quad = lane >> 4;
  const long m0 = (long)blockIdx.y * 128;
  const long n0 = (long)blockIdx.x * 128;

  v4f acc[4][4];
#pragma unroll
  for (int i = 0; i < 4; i++)
#pragma unroll
    for (int j = 0; j < 4; j++)
#pragma unroll
      for (int r = 0; r < 4; r++) acc[i][j][r] = 0.f;

  const int  srow = wave * 8 + (lane >> 3);
  const int  gcol = ((lane & 7) ^ (lane >> 3)) << 3;
  const f16* Ag = A  + (m0 + srow) * (long)K + gcol;
  const f16* Bg = Bt + (n0 + srow) * (long)K + gcol;

  const int c0q = ((quad ^ (m16 & 7)) << 3);   // phys col (f16), k-half 0
  const int c1q = c0q ^ 32;                    // k-half 1

  for (int k0 = 0; k0 < K; k0 += 64) {
#pragma unroll
    for (int g = 0; g < 4; ++g) {
      gload_lds16(Ag + (long)(g * 32) * K, &As[wave * 8 + g * 32][0]);
      gload_lds16(Bg + (long)(g * 32) * K, &Bs[wave * 8 + g * 32][0]);
    }
    Ag += 64; Bg += 64;
    __syncthreads();                // drains vmcnt -> staged tile visible
    v8h af[4], bfr[4];
#pragma unroll
    for (int i = 0; i < 4; i++) af[i]  = *(const v8h*)&As[wm + i * 16 + m16][c0q];
#pragma unroll
    for (int j = 0; j < 4; j++) bfr[j] = *(const v8h*)&Bs[wn + j * 16 + m16][c0q];
#pragma unroll
    for (int i = 0; i < 4; i++)
#pragma unroll
      for (int j = 0; j < 4; j++)
        acc[i][j] = __builtin_amdgcn_mfma_f32_16x16x32_f16(af[i], bfr[j], acc[i][j], 0, 0, 0);
#pragma unroll
    for (int i = 0; i < 4; i++) af[i]  = *(const v8h*)&As[wm + i * 16 + m16][c1q];
#pragma unroll
    for (int j = 0; j < 4; j++) bfr[j] = *(const v8h*)&Bs[wn + j * 16 + m16][c1q];
#pragma unroll
    for (int i = 0; i < 4; i++)
#pragma unroll
      for (int j = 0; j < 4; j++)
        acc[i][j] = __builtin_amdgcn_mfma_f32_16x16x32_f16(af[i], bfr[j], acc[i][j], 0, 0, 0);
    __syncthreads();                // protect LDS before next stage
  }

#pragma unroll
  for (int i = 0; i < 4; i++) {
#pragma unroll
    for (int j = 0; j < 4; j++) {
      const long n = n0 + wn + j * 16 + m16;
      const float bv = bias[n];
#pragma unroll
      for (int r = 0; r < 4; r++) {
        const long m = m0 + wm + i * 16 + quad * 4 + r;
        float v = acc[i][j][r] + bv;
        if (F16OUT) ((f16*)Cv)[m * N + n] = (f16)v;
        else        ((float*)Cv)[m * N + n] = v;
      }
    }
  }
}

// ---------------- MFMA GEMM BM=256 (R9-proven config for GEMM2) ----------------
template <bool F16OUT>
__launch_bounds__(256, 2)
__global__ void k_gemm_big(const f16* __restrict__ A, const f16* __restrict__ Bt,
                           const float* __restrict__ bias, void* __restrict__ Cv,
                           int M, int N, int K) {
  __shared__ f16 As[256][64];   // 32 KB
  __shared__ f16 Bs[128][64];   // 16 KB
  const int tid  = threadIdx.x;
  const int lane = tid & 63;
  const int wave = tid >> 6;
  const int wm   = (wave >> 1) * 128;   // wave row base (2 waves in M)
  const int wn   = (wave & 1) * 64;     // wave col base (2 waves in N)
  const int m16  = lane & 15;
  const int quad = lane >> 4;
  const long m0 = (long)blockIdx.y * 256;
  const long n0 = (long)blockIdx.x * 128;

  v4f acc[8][4];
#pragma unroll
  for (int i = 0; i < 8; i++)
#pragma unroll
    for (int j = 0; j < 4; j++)
#pragma unroll
      for (int r = 0; r < 4; r++) acc[i][j][r] = 0.f;

  const int  srow = wave * 8 + (lane >> 3);
  const int  gcol = ((lane & 7) ^ (lane >> 3)) << 3;
  const f16* Ag = A  + (m0 + srow) * (long)K + gcol;
  const f16* Bg = Bt + (n0 + srow) * (long)K + gcol;
  f16* AsW = &As[wave * 8][0];   // wave-uniform dest bases
  f16* BsW = &Bs[wave * 8][0];

  const int c0q = ((quad ^ (m16 & 7)) << 3);   // phys col (f16), k-half 0
  const int c1q = c0q ^ 32;                    // k-half 1

  for (int k0 = 0; k0 < K; k0 += 64) {
#pragma unroll
    for (int g = 0; g < 8; ++g)
      gload_lds16(Ag + (long)(g * 32) * K, AsW + g * 32 * 64);
#pragma unroll
    for (int g = 0; g < 4; ++g)
      gload_lds16(Bg + (long)(g * 32) * K, BsW + g * 32 * 64);
    Ag += 64; Bg += 64;
    __syncthreads();
    v8h bfr[4], af;
#pragma unroll
    for (int j = 0; j < 4; j++) bfr[j] = *(const v8h*)&Bs[wn + j * 16 + m16][c0q];
#pragma unroll
    for (int i = 0; i < 8; i++) {
      af = *(const v8h*)&As[wm + i * 16 + m16][c0q];
#pragma unroll
      for (int j = 0; j < 4; j++)
        acc[i][j] = __builtin_amdgcn_mfma_f32_16x16x32_f16(af, bfr[j], acc[i][j], 0, 0, 0);
    }
#pragma unroll
    for (int j = 0; j < 4; j++) bfr[j] = *(const v8h*)&Bs[wn + j * 16 + m16][c1q];
#pragma unroll
    for (int i = 0; i < 8; i++) {
      af = *(const v8h*)&As[wm + i * 16 + m16][c1q];
#pragma unroll
      for (int j = 0; j < 4; j++)
        acc[i][j] = __builtin_amdgcn_mfma_f32_16x16x32_f16(af, bfr[j], acc[i][j], 0, 0, 0);
    }
    __syncthreads();
  }

#pragma unroll
  for (int i = 0; i < 8; i++) {
#pragma unroll
    for (int j = 0; j < 4; j++) {
      const long n = n0 + wn + j * 16 + m16;
      const float bv = bias[n];
#pragma unroll
      for (int r = 0; r < 4; r++) {
        const long m = m0 + wm + i * 16 + quad * 4 + r;
        float v = acc[i][j][r] + bv;
        if (F16OUT) ((f16*)Cv)[m * N + n] = (f16)v;
        else        ((float*)Cv)[m * N + n] = v;
      }
    }
  }
}

// ---------------- conv4 + SiLU + EMA scan + gate (R11: register prefetch) ----------------
// [m][c] layout (wave-coalesced: consecutive lanes -> consecutive channels).
// Window 64 (R9-proven occupancy fix). NEW: explicit 1-batch-ahead register
// prefetch -- batch k+1's 8(+8) scalar loads are issued BEFORE processing
// batch k, so the ~330cy of per-batch VALU covers the load latency (R9's
// VGPR=20 showed the compiler kept almost nothing in flight). All arrays
// fully statically indexed (full unroll) -> registers, no scratch.
__launch_bounds__(256, 4)
__global__ void k_conv_scan(const f16* __restrict__ xz, const float* __restrict__ conv_w,
                            const float* __restrict__ conv_b, const float* __restrict__ Dp_,
                            f16* __restrict__ y) {
  const int tid = threadIdx.x;
  const int c   = blockIdx.y * 256 + tid;
  const int b   = blockIdx.z;
  const int t0  = blockIdx.x * 64;     // output window [t0, t0+64)
  const float w0 = conv_w[c * 4 + 0], w1 = conv_w[c * 4 + 1];
  const float w2 = conv_w[c * 4 + 2], w3 = conv_w[c * 4 + 3];
  const float cb = conv_b[c], Dp = Dp_[c];
  const long mb = (long)b * SEQ;

  const f16* xcol = xz + mb * (long)NXZ + c;            // x[t][c] = xcol[t*NXZ]
  const f16* zcol = xcol + D_INNER;                     // z[t][c]
  f16*       ycol = y  + (mb + t0) * (long)D_INNER + c; // y[t0+u][c]

  float xm3 = 0.f, xm2 = 0.f, xm1 = 0.f, h = 0.f;
  const int ts = t0 - WARM;

  f16 xc[8], zc[8], xn[8], zn[8];

#define LDX8(D, T) { _Pragma("unroll") for (int e = 0; e < 8; ++e) D[e] = xcol[(long)((T) + e) * NXZ]; }
#define LDZ8(D, T) { _Pragma("unroll") for (int e = 0; e < 8; ++e) D[e] = zcol[(long)((T) + e) * NXZ]; }

  if (t0 > 0) {
    // garbage-for-pad at ts-3<0 decays by 0.9^61 (R8/R9-proven semantics)
    xm3 = (float)xcol[(long)(ts - 3) * NXZ];
    xm2 = (float)xcol[(long)(ts - 2) * NXZ];
    xm1 = (float)xcol[(long)(ts - 1) * NXZ];
    LDX8(xc, ts)
    // warm-up: 8 batches, EMA only; prefetch next batch under current compute
#pragma unroll
    for (int k = 0; k < 8; ++k) {
      if (k < 7) { LDX8(xn, ts + (k + 1) * 8) }
      else       { LDX8(xn, t0) LDZ8(zn, t0) }   // prefetch main batch 0
#pragma unroll
      for (int e = 0; e < 8; ++e) {
        float xt = (float)xc[e];
        float u  = w0 * xm3 + w1 * xm2 + w2 * xm1 + w3 * xt + cb;
        h = 0.9f * h + 0.1f * fsilu(u);
        xm3 = xm2; xm2 = xm1; xm1 = xt;
      }
#pragma unroll
      for (int e = 0; e < 8; ++e) xc[e] = xn[e];
    }
#pragma unroll
    for (int e = 0; e < 8; ++e) zc[e] = zn[e];
  } else {
    LDX8(xc, t0) LDZ8(zc, t0)      // t0==0: zero left-pad, h starts 0
  }

  // main: 8 batches of 8 outputs; prefetch batch k+1 under batch k's compute
#pragma unroll
  for (int k = 0; k < 8; ++k) {
    if (k < 7) { LDX8(xn, t0 + (k + 1) * 8) LDZ8(zn, t0 + (k + 1) * 8) }
#pragma unroll
    for (int e = 0; e < 8; ++e) {
      float xt = (float)xc[e];
      float u  = w0 * xm3 + w1 * xm2 + w2 * xm1 + w3 * xt + cb;
      float v  = fsilu(u);
      h = 0.9f * h + 0.1f * v;
      ycol[(long)(k * 8 + e) * D_INNER] = (f16)((v * Dp + h) * fsilu((float)zc[e]));
      xm3 = xm2; xm2 = xm1; xm1 = xt;
    }
    if (k < 7) {
#pragma unroll
      for (int e = 0; e < 8; ++e) { xc[e] = xn[e]; zc[e] = zn[e]; }
    }
  }
#undef LDX8
#undef LDZ8
}

// ---------------- launch ----------------
extern "C" void kernel_launch(void* const* d_in, const int* in_sizes, int n_in,
                              void* d_out, int out_size, void* d_ws, size_t ws_size,
                              hipStream_t stream) {
  const float* x       = (const float*)d_in[0];
  const float* in_w    = (const float*)d_in[1];
  const float* in_b    = (const float*)d_in[2];
  const float* conv_w  = (const float*)d_in[3];
  const float* conv_b  = (const float*)d_in[4];
  // d_in[5..8] (xp_w, xp_b, dt_w, dt_b) are dead code in the reference
  const float* D_param = (const float*)d_in[9];
  const float* out_w   = (const float*)d_in[10];
  const float* out_b   = (const float*)d_in[11];
  float* out = (float*)d_out;

  char* p = (char*)d_ws;
  f16* xb    = (f16*)p; p += (size_t)MTOT * D_MODEL * 2;   // 25.2 MB
  f16* wInT  = (f16*)p; p += (size_t)NXZ * D_MODEL * 2;    //  4.7 MB
  f16* wOutT = (f16*)p; p += (size_t)D_MODEL * D_INNER * 2;//  2.4 MB
  f16* xzb   = (f16*)p; p += (size_t)MTOT * NXZ * 2;       // 100.7 MB ([m][n])
  f16* yb    = (f16*)p; p += (size_t)MTOT * D_INNER * 2;   // 50.3 MB ([m][c])

  // fused prep: cvt + both weight transposes
  k_prep<<<NCVT + NT1 + NT2, 256, 0, stream>>>(x, xb, in_w, wInT, out_w, wOutT);

  // xz = x @ in_w + in_b (f16, [m][n]); R2-exact proven config
  k_gemm_bt<true><<<dim3(NXZ / 128, MTOT / 128), 256, 0, stream>>>(xb, wInT, in_b, xzb, MTOT, NXZ, D_MODEL);

  // conv + silu + EMA scan + gate -> y (f16, [m][c]); 64-t window + reg prefetch
  k_conv_scan<<<dim3(SEQ / 64, D_INNER / 256, BATCH), 256, 0, stream>>>(xzb, conv_w, conv_b, D_param, yb);

  // out = y @ out_w + out_b (f32, [m][n]); BM=256 (R9-proven config)
  k_gemm_big<false><<<dim3(D_MODEL / 128, MTOT / 256), 256, 0, stream>>>(yb, wOutT, out_b, out, MTOT, D_MODEL, D_INNER);
}